// Round 1
// baseline (85.792 us; speedup 1.0000x reference)
//
#include <hip/hip_runtime.h>
#include <math.h>

#define FRAME_W 1920.0f
#define FRAME_H 1080.0f
#define COEF 0.2f

// Single-thread scalar kernel: the whole reference is ~300 FLOPs on <60 floats.
// One block of 64 threads (wave-aligned), lane 0 computes everything.
__global__ void __launch_bounds__(64)
OverallLoss_36009005810130_kernel(const float* __restrict__ Rotation,  // [9]
                                  const float* __restrict__ center,    // [2]
                                  const float* __restrict__ bbox,      // [4]
                                  const float* __restrict__ bbox_3d,   // [6]
                                  const float* __restrict__ ER,        // [9]
                                  const float* __restrict__ et,        // [3]
                                  const float* __restrict__ K,         // [9]
                                  const float* __restrict__ kx,        // [1]
                                  const float* __restrict__ ky,        // [1]
                                  const float* __restrict__ beta,      // [1]
                                  const float* __restrict__ t,         // [3]
                                  const float* __restrict__ Rq,        // [4]
                                  const float* __restrict__ s,         // [3]
                                  const float* __restrict__ s_cls,     // [3]
                                  float* __restrict__ out)             // [6]
{
    if (threadIdx.x != 0) return;

    // ---- quaternion -> rotation matrix (R_mat) ----
    float r0 = Rq[0], r1 = Rq[1], r2 = Rq[2], r3 = Rq[3];
    float rn = sqrtf(r0 * r0 + r1 * r1 + r2 * r2 + r3 * r3);
    float x0 = r0 / rn, x1 = r1 / rn, x2 = r2 / rn, x3 = r3 / rn;
    float Rm[3][3];
    Rm[0][0] = 1.f - 2.f * (x1 * x1 + x2 * x2);
    Rm[0][1] = 2.f * (x0 * x1 - x2 * x3);
    Rm[0][2] = 2.f * (x0 * x2 + x1 * x3);
    Rm[1][0] = 2.f * (x0 * x1 + x2 * x3);
    Rm[1][1] = 1.f - 2.f * (x0 * x0 + x2 * x2);
    Rm[1][2] = 2.f * (x1 * x2 - x0 * x3);
    Rm[2][0] = 2.f * (x0 * x2 - x1 * x3);
    Rm[2][1] = 2.f * (x1 * x2 + x0 * x3);
    Rm[2][2] = 1.f - 2.f * (x0 * x0 + x1 * x1);

    // ---- ER and its inverse (adjugate). ext=[[ER,0],[et,1]] =>
    //      inv(ext)=[[ERinv,0],[-et@ERinv,1]]; cam = (p - et) @ ERinv ----
    float e00 = ER[0], e01 = ER[1], e02 = ER[2];
    float e10 = ER[3], e11 = ER[4], e12 = ER[5];
    float e20 = ER[6], e21 = ER[7], e22 = ER[8];
    float det = e00 * (e11 * e22 - e12 * e21)
              - e01 * (e10 * e22 - e12 * e20)
              + e02 * (e10 * e21 - e11 * e20);
    float id = 1.f / det;
    float Ei[3][3];
    Ei[0][0] = (e11 * e22 - e12 * e21) * id;
    Ei[0][1] = (e02 * e21 - e01 * e22) * id;
    Ei[0][2] = (e01 * e12 - e02 * e11) * id;
    Ei[1][0] = (e12 * e20 - e10 * e22) * id;
    Ei[1][1] = (e00 * e22 - e02 * e20) * id;
    Ei[1][2] = (e02 * e10 - e00 * e12) * id;
    Ei[2][0] = (e10 * e21 - e11 * e20) * id;
    Ei[2][1] = (e01 * e20 - e00 * e21) * id;
    Ei[2][2] = (e00 * e11 - e01 * e10) * id;

    float t0 = t[0], t1 = t[1], t2 = t[2];
    float et0 = et[0], et1 = et[1], et2 = et[2];
    float s0 = s[0], s1 = s[1], s2 = s[2];

    // ---- 8 corners -> project -> min/max ----
    float minx = INFINITY, maxx = -INFINITY;
    float miny = INFINITY, maxy = -INFINITY;
    float K00 = K[0], K01 = K[1], K02 = K[2];
    float K10 = K[3], K11 = K[4], K12 = K[5];

    for (int c = 0; c < 8; ++c) {
        // CORNER_IDX: i0 = (c>>2)?1:0 ; i1 = 2+((c>>1)&1) ; i2 = 4+(c&1)
        float cx = bbox_3d[(c >> 2) & 1] * s0;
        float cy = bbox_3d[2 + ((c >> 1) & 1)] * s1;
        float cz = bbox_3d[4 + (c & 1)] * s2;
        // p = Rm @ c + t   (corners @ Rm.T)
        float p0 = Rm[0][0] * cx + Rm[0][1] * cy + Rm[0][2] * cz + t0;
        float p1 = Rm[1][0] * cx + Rm[1][1] * cy + Rm[1][2] * cz + t1;
        float p2 = Rm[2][0] * cx + Rm[2][1] * cy + Rm[2][2] * cz + t2;
        // cam = (p - et) @ Ei   (row-vector convention)
        float d0 = p0 - et0, d1 = p1 - et1, d2 = p2 - et2;
        float c0 = d0 * Ei[0][0] + d1 * Ei[1][0] + d2 * Ei[2][0];
        float c1 = d0 * Ei[0][1] + d1 * Ei[1][1] + d2 * Ei[2][1];
        float c2 = d0 * Ei[0][2] + d1 * Ei[1][2] + d2 * Ei[2][2];
        // perspective divide
        float iz = 1.f / c2;
        c0 *= iz; c1 *= iz;  // c2 becomes 1
        // pix = cam @ K.T
        float px = K00 * c0 + K01 * c1 + K02;
        float py = K10 * c0 + K11 * c1 + K12;
        minx = fminf(minx, px); maxx = fmaxf(maxx, px);
        miny = fminf(miny, py); maxy = fmaxf(maxy, py);
    }

    float bbox2d0 = minx / FRAME_W;
    float bbox2d1 = maxx / FRAME_W;
    float bbox2d2 = miny / FRAME_H;
    float bbox2d3 = maxy / FRAME_H;

    // ---- world-center path: cc = inv(K) @ [beta*kx*W, beta*ky*H, beta] ----
    float k00 = K[0], k01 = K[1], k02 = K[2];
    float k10 = K[3], k11 = K[4], k12 = K[5];
    float k20 = K[6], k21 = K[7], k22 = K[8];
    float kdet = k00 * (k11 * k22 - k12 * k21)
               - k01 * (k10 * k22 - k12 * k20)
               + k02 * (k10 * k21 - k11 * k20);
    float ikd = 1.f / kdet;
    float Ki[3][3];
    Ki[0][0] = (k11 * k22 - k12 * k21) * ikd;
    Ki[0][1] = (k02 * k21 - k01 * k22) * ikd;
    Ki[0][2] = (k01 * k12 - k02 * k11) * ikd;
    Ki[1][0] = (k12 * k20 - k10 * k22) * ikd;
    Ki[1][1] = (k00 * k22 - k02 * k20) * ikd;
    Ki[1][2] = (k02 * k10 - k00 * k12) * ikd;
    Ki[2][0] = (k10 * k21 - k11 * k20) * ikd;
    Ki[2][1] = (k01 * k20 - k00 * k21) * ikd;
    Ki[2][2] = (k00 * k11 - k01 * k10) * ikd;

    float bev = beta[0], kxv = kx[0], kyv = ky[0];
    float v0 = bev * kxv * FRAME_W;
    float v1 = bev * kyv * FRAME_H;
    float v2 = bev;
    float cc0 = Ki[0][0] * v0 + Ki[0][1] * v1 + Ki[0][2] * v2;
    float cc1 = Ki[1][0] * v0 + Ki[1][1] * v1 + Ki[1][2] * v2;
    float cc2 = Ki[2][0] * v0 + Ki[2][1] * v1 + Ki[2][2] * v2;

    // world = (cc4 @ ext)[:3]  ->  world[j] = sum_i cc_i * ER[i][j] + et[j]
    float w0 = cc0 * e00 + cc1 * e10 + cc2 * e20 + et0;
    float w1 = cc0 * e01 + cc1 * e11 + cc2 * e21 + et1;
    float w2 = cc0 * e02 + cc1 * e12 + cc2 * e22 + et2;

    // ---- losses ----
    float pixel_center_loss =
        0.5f * (fabsf(kxv - center[0]) + fabsf(kyv - center[1]));

    float world_center_loss =
        (fabsf(w0 - t0) + fabsf(w1 - t1) + fabsf(w2 - t2)) * (1.f / 3.f);

    // rotation_loss = mean((Rotation - ER @ Rm)^2)
    float rot_acc = 0.f;
    for (int i = 0; i < 3; ++i) {
        float Ei0 = ER[3 * i + 0], Ei1 = ER[3 * i + 1], Ei2 = ER[3 * i + 2];
        for (int j = 0; j < 3; ++j) {
            float m = Ei0 * Rm[0][j] + Ei1 * Rm[1][j] + Ei2 * Rm[2][j];
            float dd = Rotation[3 * i + j] - m;
            rot_acc += dd * dd;
        }
    }
    float rotation_loss = rot_acc * (1.f / 9.f);

    float scale_bbox_loss = 0.25f * (fabsf(bbox2d0 - bbox[0]) +
                                     fabsf(bbox2d1 - bbox[1]) +
                                     fabsf(bbox2d2 - bbox[2]) +
                                     fabsf(bbox2d3 - bbox[3]));

    float scale_cls_loss = (fabsf(s0 - s_cls[0]) +
                            fabsf(s1 - s_cls[1]) +
                            fabsf(s2 - s_cls[2])) * (1.f / 3.f);

    float overall = COEF * (pixel_center_loss + world_center_loss +
                            rotation_loss + scale_bbox_loss + scale_cls_loss);

    out[0] = overall;
    out[1] = pixel_center_loss;
    out[2] = world_center_loss;
    out[3] = rotation_loss;
    out[4] = scale_bbox_loss;
    out[5] = scale_cls_loss;
}

extern "C" void kernel_launch(void* const* d_in, const int* in_sizes, int n_in,
                              void* d_out, int out_size, void* d_ws, size_t ws_size,
                              hipStream_t stream) {
    (void)in_sizes; (void)n_in; (void)d_ws; (void)ws_size; (void)out_size;
    const float* Rotation = (const float*)d_in[0];
    const float* center   = (const float*)d_in[1];
    const float* bbox     = (const float*)d_in[2];
    const float* bbox_3d  = (const float*)d_in[3];
    const float* ER       = (const float*)d_in[4];
    const float* et       = (const float*)d_in[5];
    const float* K        = (const float*)d_in[6];
    const float* kx       = (const float*)d_in[7];
    const float* ky       = (const float*)d_in[8];
    const float* beta     = (const float*)d_in[9];
    const float* t        = (const float*)d_in[10];
    const float* Rq       = (const float*)d_in[11];
    const float* s        = (const float*)d_in[12];
    const float* s_cls    = (const float*)d_in[13];
    float* out = (float*)d_out;

    OverallLoss_36009005810130_kernel<<<1, 64, 0, stream>>>(
        Rotation, center, bbox, bbox_3d, ER, et, K, kx, ky, beta, t, Rq, s, s_cls, out);
}